// Round 19
// baseline (371.205 us; speedup 1.0000x reference)
//
#include <hip/hip_runtime.h>
#include <cstdint>

typedef unsigned int u32;
typedef unsigned short u16;

#define NN 50000
#define NE 1600000
#define LDA0 288           // A0 row stride in u16 (576B = 9 lines, odd -> all L2 sets)

#define NPART 196          // partition = dst >> 8 (256 nodes each; 196*256 = 50176)
#define SPAN1 2048
#define NB1 ((NE + SPAN1 - 1) / SPAN1)    // 782

typedef __bf16 bf16x8 __attribute__((ext_vector_type(8)));
typedef float f32x16 __attribute__((ext_vector_type(16)));

// ---------------- threefry2x32-20 ----------------
__host__ __device__ static inline void tf2x32(u32 ka, u32 kb, u32 x0, u32 x1,
                                              u32& o0, u32& o1) {
  const u32 kc = ka ^ kb ^ 0x1BD11BDAu;
  u32 v0 = x0 + ka, v1 = x1 + kb;
#define TFR(r) { v0 += v1; v1 = (v1 << (r)) | (v1 >> (32 - (r))); v1 ^= v0; }
  TFR(13) TFR(15) TFR(26) TFR(6)   v0 += kb; v1 += kc + 1u;
  TFR(17) TFR(29) TFR(16) TFR(24)  v0 += kc; v1 += ka + 2u;
  TFR(13) TFR(15) TFR(26) TFR(6)   v0 += ka; v1 += kb + 3u;
  TFR(17) TFR(29) TFR(16) TFR(24)  v0 += kb; v1 += kc + 4u;
  TFR(13) TFR(15) TFR(26) TFR(6)   v0 += kc; v1 += ka + 5u;
#undef TFR
  o0 = v0; o1 = v1;
}

__device__ static inline u32 tfbits(u32 ka, u32 kb, u32 j) {
  u32 o0, o1;
  tf2x32(ka, kb, 0u, j, o0, o1);
  return o0 ^ o1;
}

__device__ static inline float u01(u32 bits) {
  return __uint_as_float((bits >> 9) | 0x3f800000u) - 1.0f;
}
__device__ static inline u16 f2bf(float f) {  // RNE
  u32 u = __float_as_uint(f);
  return (u16)((u + 0x7fffu + ((u >> 16) & 1u)) >> 16);
}
__device__ static inline float bflo(u32 w) { return __uint_as_float(w << 16); }
__device__ static inline float bfhi(u32 w) { return __uint_as_float(w & 0xffff0000u); }

// ---------------- fused prologue: drop0 | compact(+inline detect) | prep_w ----------------
#define PRO_DROP 12500
#define PRO_COMP 18750
#define PRO_TOT  19518

__global__ __launch_bounds__(256) void prologue_kernel(
    const float* __restrict__ x, const int* __restrict__ ei,
    const float* __restrict__ wr0, const float* __restrict__ wroot0,
    const float* __restrict__ wr1, const float* __restrict__ wroot1,
    u16* __restrict__ A0, u32* __restrict__ epack,
    u16* __restrict__ Wt0, u16* __restrict__ Wt1,
    u32 ka, u32 kb) {
  int bid = blockIdx.x;
  int tid = threadIdx.x;
  if (bid < PRO_DROP) {
    int j0 = (bid * 256 + tid) * 2;        // [0, 6.4M), even
    float v0 = (u01(tfbits(ka, kb, (u32)j0)) < 0.4f) ? x[j0] * 2.5f : 0.0f;
    float v1 = (u01(tfbits(ka, kb, (u32)j0 + 1u)) < 0.4f) ? x[j0 + 1] * 2.5f : 0.0f;
    int r = j0 >> 7, c = j0 & 127;         // c even -> same row
    *(u32*)&A0[r * LDA0 + 128 + c] = (u32)f2bf(v0) | ((u32)f2bf(v1) << 16);
  } else if (bid < PRO_COMP) {
    __shared__ int s_nz;
    if (tid == 0) s_nz = 0;
    __syncthreads();
    if (ei[2 * (tid & 127) + 1] != 0) s_nz = 1;
    __syncthreads();
    int f = s_nz ? 0 : 1;                  // 1 -> int64 LE layout
    int i = (bid - PRO_DROP) * 256 + tid;  // [0, NE)
    int s = f ? ei[2 * (size_t)i] : ei[i];
    int d = f ? ei[2 * ((size_t)NE + i)] : ei[(size_t)NE + i];
    epack[i] = (u32)s | ((u32)d << 16);
  } else {
    int i = (bid - PRO_COMP) * 256 + tid;
    if (i < 256 * 256) {                   // Wt0: [n=256][k=256]
      int n = i >> 8, k = i & 255;
      float v = (k < 128) ? wr0[k * 256 + n] : wroot0[(k - 128) * 256 + n];
      Wt0[n * 256 + k] = f2bf(v);
    }
    int j = i - 256 * 256;
    if (j >= 0 && j < 256 * 512) {         // Wt1: [n=256][k=512]
      int n = j >> 9, k = j & 511;
      float v = (k < 256) ? wr1[k * 256 + n] : wroot1[(k - 256) * 256 + n];
      Wt1[n * 512 + k] = f2bf(v);
    }
  }
}

// ---------------- P1: per-block partition counts (LDS histogram) ----------------
__global__ __launch_bounds__(256) void p1_count_kernel(const u32* __restrict__ epack,
                                                       u32* __restrict__ pcnt) {
  __shared__ u32 cnt[NPART];
  int b = blockIdx.x, t = threadIdx.x;
  if (t < NPART) cnt[t] = 0;
  __syncthreads();
  int base = b * SPAN1;
#pragma unroll
  for (int k = 0; k < SPAN1 / 256; k++) {
    int i = base + k * 256 + t;
    if (i < NE) atomicAdd(&cnt[epack[i] >> 24], 1);   // d>>8 == epack>>24
  }
  __syncthreads();
  if (t < NPART) pcnt[b * NPART + t] = cnt[t];
}

// ---------------- P1b: exclusive scan over blocks, per partition ----------------
__global__ __launch_bounds__(256) void p1b_scan_kernel(const u32* __restrict__ pcnt,
                                                       u32* __restrict__ pofs,
                                                       u32* __restrict__ psize) {
  __shared__ u32 sc[256];
  int p = blockIdx.x, t = threadIdx.x;
  u32 val[4];
  u32 tsum = 0;
#pragma unroll
  for (int k = 0; k < 4; k++) {
    int b = t * 4 + k;
    val[k] = (b < NB1) ? pcnt[b * NPART + p] : 0;
    tsum += val[k];
  }
  sc[t] = tsum;
  __syncthreads();
#pragma unroll
  for (int d = 1; d < 256; d <<= 1) {
    u32 x = (t >= d) ? sc[t - d] : 0;
    __syncthreads();
    sc[t] += x;
    __syncthreads();
  }
  u32 run = sc[t] - tsum;
#pragma unroll
  for (int k = 0; k < 4; k++) {
    int b = t * 4 + k;
    if (b < NB1) { pofs[p * NB1 + b] = run; run += val[k]; }
  }
  if (t == 255) psize[p] = sc[255];
}

// ---------------- P1d: partition-scatter (LDS cursors; pbase from LDS scan) ----------------
__global__ __launch_bounds__(256) void p1d_pscatter_kernel(const u32* __restrict__ epack,
                                                           const u32* __restrict__ pofs,
                                                           const u32* __restrict__ psize,
                                                           u32* __restrict__ part_buf) {
  __shared__ u32 sc[256];
  __shared__ u32 cur[NPART];
  int b = blockIdx.x, t = threadIdx.x;
  u32 v = (t < NPART) ? psize[t] : 0;
  sc[t] = v;
  __syncthreads();
#pragma unroll
  for (int d = 1; d < 256; d <<= 1) {
    u32 x = (t >= d) ? sc[t - d] : 0;
    __syncthreads();
    sc[t] += x;
    __syncthreads();
  }
  if (t < NPART) cur[t] = (sc[t] - v) + pofs[t * NB1 + b];
  __syncthreads();
  int base = b * SPAN1;
#pragma unroll
  for (int k = 0; k < SPAN1 / 256; k++) {
    int i = base + k * 256 + t;
    if (i < NE) {
      u32 e = epack[i];
      u32 p = e >> 24;
      u32 slot = atomicAdd(&cur[p], 1);
      part_buf[slot] = (e & 0xffffu) | (((e >> 16) & 255u) << 16);  // src | dlow<<16
    }
  }
}

// ---------------- P2: per-partition local sort -> offs + ssrc ----------------
__global__ __launch_bounds__(256) void p2_sort_kernel(const u32* __restrict__ part_buf,
                                                      const u32* __restrict__ psize,
                                                      int* __restrict__ offs,
                                                      u16* __restrict__ ssrc) {
  __shared__ u32 sc[256], cnt[256], cur[256];
  __shared__ u32 s_pb;
  int p = blockIdx.x, t = threadIdx.x;
  // pbase[p] via LDS scan of psize
  u32 v = (t < NPART) ? psize[t] : 0;
  sc[t] = v;
  __syncthreads();
#pragma unroll
  for (int d = 1; d < 256; d <<= 1) {
    u32 x = (t >= d) ? sc[t - d] : 0;
    __syncthreads();
    sc[t] += x;
    __syncthreads();
  }
  if (t == p) s_pb = sc[t] - v;
  cnt[t] = 0;
  __syncthreads();
  u32 pb = s_pb;
  int sz = (int)psize[p];
  for (int i = t; i < sz; i += 256)
    atomicAdd(&cnt[(part_buf[pb + i] >> 16) & 255u], 1);
  __syncthreads();
  u32 val = cnt[t];
  sc[t] = val;
  __syncthreads();
#pragma unroll
  for (int d = 1; d < 256; d <<= 1) {
    u32 x = (t >= d) ? sc[t - d] : 0;
    __syncthreads();
    sc[t] += x;
    __syncthreads();
  }
  u32 excl = sc[t] - val;
  int node = (p << 8) + t;
  if (node <= NN) offs[node] = (int)(pb + excl);
  cur[t] = excl;
  __syncthreads();
  for (int i = t; i < sz; i += 256) {
    u32 w = part_buf[pb + i];
    u32 slot = atomicAdd(&cur[(w >> 16) & 255u], 1);
    ssrc[pb + slot] = (u16)(w & 0xffffu);
  }
}

// ---------------- aggregation: full-row uint4 gather, wave per node ----------------
// Integer-grid accumulation: quantize to 2^-K grid, add integers in fp32 (all
// partials < 2^24 -> every add exact -> order-independent/deterministic).
#define ACC8Q(V, S) { acc[0] += rintf(bflo(V.x) * S); acc[1] += rintf(bfhi(V.x) * S); \
                      acc[2] += rintf(bflo(V.y) * S); acc[3] += rintf(bfhi(V.y) * S); \
                      acc[4] += rintf(bflo(V.z) * S); acc[5] += rintf(bfhi(V.z) * S); \
                      acc[6] += rintf(bflo(V.w) * S); acc[7] += rintf(bfhi(V.w) * S); }

// agg0: A0 [NN][LDA0], gather h0 (cols 128..255, 16 lanes x 16B, 4 edge-groups).
__global__ __launch_bounds__(256) void agg0_kernel(u16* __restrict__ A0,
                                                   const int* __restrict__ offs,
                                                   const u16* __restrict__ ssrc) {
  const float S = 8192.0f, INV = 1.0f / 8192.0f;   // 2^13
  int node = blockIdx.x * 4 + (threadIdx.x >> 6);
  int lane = threadIdx.x & 63;
  int l15 = lane & 15, eh = lane >> 4;    // eh in 0..3
  int s = offs[node], e = offs[node + 1];
  float acc[8] = {0.f, 0.f, 0.f, 0.f, 0.f, 0.f, 0.f, 0.f};
  int i = s;
  for (; i + 16 <= e; i += 16) {
    uint4 w0 = *(const uint4*)&A0[(int)ssrc[i + eh] * LDA0 + 128 + l15 * 8];
    uint4 w1 = *(const uint4*)&A0[(int)ssrc[i + 4 + eh] * LDA0 + 128 + l15 * 8];
    uint4 w2 = *(const uint4*)&A0[(int)ssrc[i + 8 + eh] * LDA0 + 128 + l15 * 8];
    uint4 w3 = *(const uint4*)&A0[(int)ssrc[i + 12 + eh] * LDA0 + 128 + l15 * 8];
    ACC8Q(w0, S); ACC8Q(w1, S); ACC8Q(w2, S); ACC8Q(w3, S);
  }
  for (; i + 4 <= e; i += 4) {
    uint4 w0 = *(const uint4*)&A0[(int)ssrc[i + eh] * LDA0 + 128 + l15 * 8];
    ACC8Q(w0, S);
  }
  if (i + eh < e) {
    uint4 w0 = *(const uint4*)&A0[(int)ssrc[i + eh] * LDA0 + 128 + l15 * 8];
    ACC8Q(w0, S);
  }
#pragma unroll
  for (int j = 0; j < 8; j++) {
    acc[j] += __shfl_xor(acc[j], 16);
    acc[j] += __shfl_xor(acc[j], 32);
  }
  if (lane < 16) {
    uint4 o;
    o.x = (u32)f2bf(acc[0] * INV) | ((u32)f2bf(acc[1] * INV) << 16);
    o.y = (u32)f2bf(acc[2] * INV) | ((u32)f2bf(acc[3] * INV) << 16);
    o.z = (u32)f2bf(acc[4] * INV) | ((u32)f2bf(acc[5] * INV) << 16);
    o.w = (u32)f2bf(acc[6] * INV) | ((u32)f2bf(acc[7] * INV) << 16);
    *(uint4*)&A0[node * LDA0 + l15 * 8] = o;
  }
}

// agg1: A1 [NN][512] (on d_out), gather h1 (cols 256..511, 32 lanes x 16B).
__global__ __launch_bounds__(256) void agg1_kernel(u16* __restrict__ A1,
                                                   const int* __restrict__ offs,
                                                   const u16* __restrict__ ssrc) {
  const float S = 256.0f, INV = 1.0f / 256.0f;     // 2^8
  int node = blockIdx.x * 4 + (threadIdx.x >> 6);
  int lane = threadIdx.x & 63;
  int l31 = lane & 31, eh = lane >> 5;    // eh in 0..1
  int s = offs[node], e = offs[node + 1];
  float acc[8] = {0.f, 0.f, 0.f, 0.f, 0.f, 0.f, 0.f, 0.f};
  int i = s;
  for (; i + 8 <= e; i += 8) {
    uint4 w0 = *(const uint4*)&A1[(int)ssrc[i + eh] * 512 + 256 + l31 * 8];
    uint4 w1 = *(const uint4*)&A1[(int)ssrc[i + 2 + eh] * 512 + 256 + l31 * 8];
    uint4 w2 = *(const uint4*)&A1[(int)ssrc[i + 4 + eh] * 512 + 256 + l31 * 8];
    uint4 w3 = *(const uint4*)&A1[(int)ssrc[i + 6 + eh] * 512 + 256 + l31 * 8];
    ACC8Q(w0, S); ACC8Q(w1, S); ACC8Q(w2, S); ACC8Q(w3, S);
  }
  for (; i + 2 <= e; i += 2) {
    uint4 w0 = *(const uint4*)&A1[(int)ssrc[i + eh] * 512 + 256 + l31 * 8];
    ACC8Q(w0, S);
  }
  if (i + eh < e) {
    uint4 w0 = *(const uint4*)&A1[(int)ssrc[i + eh] * 512 + 256 + l31 * 8];
    ACC8Q(w0, S);
  }
#pragma unroll
  for (int j = 0; j < 8; j++) acc[j] += __shfl_xor(acc[j], 32);
  if (eh == 0) {
    uint4 o;
    o.x = (u32)f2bf(acc[0] * INV) | ((u32)f2bf(acc[1] * INV) << 16);
    o.y = (u32)f2bf(acc[2] * INV) | ((u32)f2bf(acc[3] * INV) << 16);
    o.z = (u32)f2bf(acc[4] * INV) | ((u32)f2bf(acc[5] * INV) << 16);
    o.w = (u32)f2bf(acc[6] * INV) | ((u32)f2bf(acc[7] * INV) << 16);
    *(uint4*)&A1[node * 512 + l31 * 8] = o;
  }
}

// ---------------- GEMM: C[256 rows x 256 cols per block] = A @ Wt^T + b ----------------
// 512 threads, 8 waves; wave w owns rows w*32..+32, all 256 cols (8 col-tiles).
// 32x32x16 MFMA. Wt re-read once per 256 rows (196 blocks -> 25-50 MB L2 total).
// DROP: relu -> dropout(k1) -> bf16 into outB right half (stride 512, +256)
// else: relu -> fp32 into outF (stride 256). A==outF aliasing safe: block stages
// its rows to LDS before any store.
template <int K, int LDA, bool DROP>
__global__ __launch_bounds__(512) void gemm_kernel(const u16* __restrict__ A,
                                                   const u16* __restrict__ Wt,
                                                   const float* __restrict__ bias,
                                                   u16* __restrict__ outB,
                                                   float* __restrict__ outF,
                                                   u32 ka, u32 kb) {
  constexpr int BK = 64;
  constexpr int LDP = BK + 8;             // 72 u16 per LDS row
  __shared__ __align__(16) u16 Alds[256 * LDP];   // 36.9 KB
  __shared__ __align__(16) u16 Blds[256 * LDP];   // 36.9 KB
  const int tid = threadIdx.x;
  const int row0 = blockIdx.x * 256;
  const int lane = tid & 63;
  const int wid = tid >> 6;               // row group 0..7
  const int l31 = lane & 31;
  const int lkhi = (lane >> 5) * 8;

  f32x16 acc[8];
#pragma unroll
  for (int i = 0; i < 8; i++)
#pragma unroll
    for (int j = 0; j < 16; j++) acc[i][j] = 0.0f;

#pragma unroll
  for (int kc = 0; kc < K / BK; kc++) {
    // stage A: 256 rows x 8 x 16B chunks, 4 per thread
#pragma unroll
    for (int i = 0; i < 4; i++) {
      int id = tid + i * 512;
      int r = id >> 3, c = id & 7;
      int rg = row0 + r; if (rg > NN - 1) rg = NN - 1;
      *(uint4*)&Alds[r * LDP + c * 8] =
          *(const uint4*)&A[(size_t)rg * LDA + kc * BK + c * 8];
    }
    // stage B: 256 rows x 8 x 16B chunks, 4 per thread
#pragma unroll
    for (int i = 0; i < 4; i++) {
      int id = tid + i * 512;
      int r = id >> 3, c = id & 7;
      *(uint4*)&Blds[r * LDP + c * 8] =
          *(const uint4*)&Wt[(size_t)r * K + kc * BK + c * 8];
    }
    __syncthreads();
#pragma unroll
    for (int ks = 0; ks < BK / 16; ks++) {
      bf16x8 a = *(const bf16x8*)&Alds[(wid * 32 + l31) * LDP + ks * 16 + lkhi];
#pragma unroll
      for (int ct = 0; ct < 8; ct++) {
        bf16x8 b = *(const bf16x8*)&Blds[(ct * 32 + l31) * LDP + ks * 16 + lkhi];
        acc[ct] = __builtin_amdgcn_mfma_f32_32x32x16_bf16(a, b, acc[ct], 0, 0, 0);
      }
    }
    __syncthreads();
  }

  // epilogue: C/D layout (m74/m101): col = lane&31, row = (r&3)+8*(r>>2)+4*(lane>>5)
#pragma unroll
  for (int ct = 0; ct < 8; ct++) {
    int col = ct * 32 + l31;
    float bv = bias[col];
#pragma unroll
    for (int r = 0; r < 16; r++) {
      int row = row0 + wid * 32 + (r & 3) + 8 * (r >> 2) + 4 * (lane >> 5);
      if (row < NN) {
        float v = acc[ct][r] + bv;
        v = fmaxf(v, 0.0f);
        if constexpr (DROP) {
          u32 j = (u32)row * 256u + (u32)col;
          v = (u01(tfbits(ka, kb, j)) < 0.4f) ? v * 2.5f : 0.0f;
          outB[(size_t)row * 512 + 256 + col] = f2bf(v);
        } else {
          outF[(size_t)row * 256 + col] = v;
        }
      }
    }
  }
}

// ---------------- host launch ----------------
extern "C" void kernel_launch(void* const* d_in, const int* in_sizes, int n_in,
                              void* d_out, int out_size, void* d_ws, size_t ws_size,
                              hipStream_t stream) {
  (void)in_sizes; (void)n_in; (void)out_size; (void)ws_size;
  const float* x       = (const float*)d_in[0];
  const int*   ei      = (const int*)d_in[1];
  const float* w_rel0  = (const float*)d_in[2];
  const float* b_rel0  = (const float*)d_in[3];
  const float* w_root0 = (const float*)d_in[4];
  const float* w_rel1  = (const float*)d_in[5];
  const float* b_rel1  = (const float*)d_in[6];
  const float* w_root1 = (const float*)d_in[7];
  float* out = (float*)d_out;

  u32 k0a, k0b, k1a, k1b;
  tf2x32(0u, 42u, 0u, 0u, k0a, k0b);
  tf2x32(0u, 42u, 0u, 1u, k1a, k1b);

  uint8_t* p = (uint8_t*)d_ws;
  auto alloc = [&](size_t bytes) {
    uint8_t* r = p;
    p += (bytes + 255) & ~(size_t)255;
    return r;
  };
  u16* A0       = (u16*)alloc((size_t)NN * LDA0 * 2);  // 28.8 MB
  u16* Wt0      = (u16*)alloc(256 * 256 * 2);
  u16* Wt1      = (u16*)alloc(256 * 512 * 2);
  int* offs     = (int*)alloc((size_t)(NN + 1) * 4);
  u16* ssrc     = (u16*)alloc((size_t)NE * 2);
  u32* epack    = (u32*)alloc((size_t)NE * 4);
  u32* pcnt     = (u32*)alloc((size_t)NB1 * NPART * 4);
  u32* pofs     = (u32*)alloc((size_t)NPART * NB1 * 4);
  u32* psize    = (u32*)alloc((size_t)NPART * 4);
  u32* part_buf = (u32*)alloc((size_t)NE * 4);

  u16* A1 = (u16*)d_out;   // A1 [50000][512] bf16 aliases d_out

  const int GEMM_NB = (NN + 255) / 256;   // 196

  prologue_kernel<<<PRO_TOT, 256, 0, stream>>>(x, ei, w_rel0, w_root0, w_rel1,
                                               w_root1, A0, epack, Wt0, Wt1,
                                               k0a, k0b);
  p1_count_kernel<<<NB1, 256, 0, stream>>>(epack, pcnt);
  p1b_scan_kernel<<<NPART, 256, 0, stream>>>(pcnt, pofs, psize);
  p1d_pscatter_kernel<<<NB1, 256, 0, stream>>>(epack, pofs, psize, part_buf);
  p2_sort_kernel<<<NPART, 256, 0, stream>>>(part_buf, psize, offs, ssrc);
  agg0_kernel<<<12500, 256, 0, stream>>>(A0, offs, ssrc);
  gemm_kernel<256, LDA0, true><<<GEMM_NB, 512, 0, stream>>>(A0, Wt0, b_rel0, A1, nullptr, k1a, k1b);
  agg1_kernel<<<12500, 256, 0, stream>>>(A1, offs, ssrc);
  gemm_kernel<512, 512, false><<<GEMM_NB, 512, 0, stream>>>(A1, Wt1, b_rel1, nullptr, out, 0u, 0u);
}

// Round 20
// 303.671 us; speedup vs baseline: 1.2224x; 1.2224x over previous
//
#include <hip/hip_runtime.h>
#include <cstdint>

typedef unsigned int u32;
typedef unsigned short u16;

#define NN 50000
#define NE 1600000
#define LDA0 288           // A0 row stride in u16 (576B = 9 lines, odd -> all L2 sets)

#define NPART 196          // partition = dst >> 8 (256 nodes each; 196*256 = 50176)
#define SPAN1 2048
#define NB1 ((NE + SPAN1 - 1) / SPAN1)    // 782

typedef __bf16 bf16x8 __attribute__((ext_vector_type(8)));
typedef float f32x16 __attribute__((ext_vector_type(16)));

// ---------------- threefry2x32-20 ----------------
__host__ __device__ static inline void tf2x32(u32 ka, u32 kb, u32 x0, u32 x1,
                                              u32& o0, u32& o1) {
  const u32 kc = ka ^ kb ^ 0x1BD11BDAu;
  u32 v0 = x0 + ka, v1 = x1 + kb;
#define TFR(r) { v0 += v1; v1 = (v1 << (r)) | (v1 >> (32 - (r))); v1 ^= v0; }
  TFR(13) TFR(15) TFR(26) TFR(6)   v0 += kb; v1 += kc + 1u;
  TFR(17) TFR(29) TFR(16) TFR(24)  v0 += kc; v1 += ka + 2u;
  TFR(13) TFR(15) TFR(26) TFR(6)   v0 += ka; v1 += kb + 3u;
  TFR(17) TFR(29) TFR(16) TFR(24)  v0 += kb; v1 += kc + 4u;
  TFR(13) TFR(15) TFR(26) TFR(6)   v0 += kc; v1 += ka + 5u;
#undef TFR
  o0 = v0; o1 = v1;
}

__device__ static inline u32 tfbits(u32 ka, u32 kb, u32 j) {
  u32 o0, o1;
  tf2x32(ka, kb, 0u, j, o0, o1);
  return o0 ^ o1;
}

__device__ static inline float u01(u32 bits) {
  return __uint_as_float((bits >> 9) | 0x3f800000u) - 1.0f;
}
__device__ static inline u16 f2bf(float f) {  // RNE
  u32 u = __float_as_uint(f);
  return (u16)((u + 0x7fffu + ((u >> 16) & 1u)) >> 16);
}
__device__ static inline float bflo(u32 w) { return __uint_as_float(w << 16); }
__device__ static inline float bfhi(u32 w) { return __uint_as_float(w & 0xffff0000u); }

// ---------------- fused prologue: drop0 | compact(+inline detect) | prep_w ----------------
#define PRO_DROP 12500
#define PRO_COMP 18750
#define PRO_TOT  19518

__global__ __launch_bounds__(256) void prologue_kernel(
    const float* __restrict__ x, const int* __restrict__ ei,
    const float* __restrict__ wr0, const float* __restrict__ wroot0,
    const float* __restrict__ wr1, const float* __restrict__ wroot1,
    u16* __restrict__ A0, u32* __restrict__ epack,
    u16* __restrict__ Wt0, u16* __restrict__ Wt1,
    u32 ka, u32 kb) {
  int bid = blockIdx.x;
  int tid = threadIdx.x;
  if (bid < PRO_DROP) {
    int j0 = (bid * 256 + tid) * 2;        // [0, 6.4M), even
    float v0 = (u01(tfbits(ka, kb, (u32)j0)) < 0.4f) ? x[j0] * 2.5f : 0.0f;
    float v1 = (u01(tfbits(ka, kb, (u32)j0 + 1u)) < 0.4f) ? x[j0 + 1] * 2.5f : 0.0f;
    int r = j0 >> 7, c = j0 & 127;         // c even -> same row
    *(u32*)&A0[r * LDA0 + 128 + c] = (u32)f2bf(v0) | ((u32)f2bf(v1) << 16);
  } else if (bid < PRO_COMP) {
    __shared__ int s_nz;
    if (tid == 0) s_nz = 0;
    __syncthreads();
    if (ei[2 * (tid & 127) + 1] != 0) s_nz = 1;
    __syncthreads();
    int f = s_nz ? 0 : 1;                  // 1 -> int64 LE layout
    int i = (bid - PRO_DROP) * 256 + tid;  // [0, NE)
    int s = f ? ei[2 * (size_t)i] : ei[i];
    int d = f ? ei[2 * ((size_t)NE + i)] : ei[(size_t)NE + i];
    epack[i] = (u32)s | ((u32)d << 16);
  } else {
    int i = (bid - PRO_COMP) * 256 + tid;
    if (i < 256 * 256) {                   // Wt0: [n=256][k=256]
      int n = i >> 8, k = i & 255;
      float v = (k < 128) ? wr0[k * 256 + n] : wroot0[(k - 128) * 256 + n];
      Wt0[n * 256 + k] = f2bf(v);
    }
    int j = i - 256 * 256;
    if (j >= 0 && j < 256 * 512) {         // Wt1: [n=256][k=512]
      int n = j >> 9, k = j & 511;
      float v = (k < 256) ? wr1[k * 256 + n] : wroot1[(k - 256) * 256 + n];
      Wt1[n * 512 + k] = f2bf(v);
    }
  }
}

// ---------------- P1: per-block partition counts (LDS histogram) ----------------
__global__ __launch_bounds__(256) void p1_count_kernel(const u32* __restrict__ epack,
                                                       u32* __restrict__ pcnt) {
  __shared__ u32 cnt[NPART];
  int b = blockIdx.x, t = threadIdx.x;
  if (t < NPART) cnt[t] = 0;
  __syncthreads();
  int base = b * SPAN1;
#pragma unroll
  for (int k = 0; k < SPAN1 / 256; k++) {
    int i = base + k * 256 + t;
    if (i < NE) atomicAdd(&cnt[epack[i] >> 24], 1);   // d>>8 == epack>>24
  }
  __syncthreads();
  if (t < NPART) pcnt[b * NPART + t] = cnt[t];
}

// ---------------- P1b: exclusive scan over blocks, per partition ----------------
__global__ __launch_bounds__(256) void p1b_scan_kernel(const u32* __restrict__ pcnt,
                                                       u32* __restrict__ pofs,
                                                       u32* __restrict__ psize) {
  __shared__ u32 sc[256];
  int p = blockIdx.x, t = threadIdx.x;
  u32 val[4];
  u32 tsum = 0;
#pragma unroll
  for (int k = 0; k < 4; k++) {
    int b = t * 4 + k;
    val[k] = (b < NB1) ? pcnt[b * NPART + p] : 0;
    tsum += val[k];
  }
  sc[t] = tsum;
  __syncthreads();
#pragma unroll
  for (int d = 1; d < 256; d <<= 1) {
    u32 x = (t >= d) ? sc[t - d] : 0;
    __syncthreads();
    sc[t] += x;
    __syncthreads();
  }
  u32 run = sc[t] - tsum;
#pragma unroll
  for (int k = 0; k < 4; k++) {
    int b = t * 4 + k;
    if (b < NB1) { pofs[p * NB1 + b] = run; run += val[k]; }
  }
  if (t == 255) psize[p] = sc[255];
}

// ---------------- P1d: partition-scatter (LDS cursors; pbase from LDS scan) ----------------
__global__ __launch_bounds__(256) void p1d_pscatter_kernel(const u32* __restrict__ epack,
                                                           const u32* __restrict__ pofs,
                                                           const u32* __restrict__ psize,
                                                           u32* __restrict__ part_buf) {
  __shared__ u32 sc[256];
  __shared__ u32 cur[NPART];
  int b = blockIdx.x, t = threadIdx.x;
  u32 v = (t < NPART) ? psize[t] : 0;
  sc[t] = v;
  __syncthreads();
#pragma unroll
  for (int d = 1; d < 256; d <<= 1) {
    u32 x = (t >= d) ? sc[t - d] : 0;
    __syncthreads();
    sc[t] += x;
    __syncthreads();
  }
  if (t < NPART) cur[t] = (sc[t] - v) + pofs[t * NB1 + b];
  __syncthreads();
  int base = b * SPAN1;
#pragma unroll
  for (int k = 0; k < SPAN1 / 256; k++) {
    int i = base + k * 256 + t;
    if (i < NE) {
      u32 e = epack[i];
      u32 p = e >> 24;
      u32 slot = atomicAdd(&cur[p], 1);
      part_buf[slot] = (e & 0xffffu) | (((e >> 16) & 255u) << 16);  // src | dlow<<16
    }
  }
}

// ---------------- P2: per-partition local sort -> offs + ssrc ----------------
__global__ __launch_bounds__(256) void p2_sort_kernel(const u32* __restrict__ part_buf,
                                                      const u32* __restrict__ psize,
                                                      int* __restrict__ offs,
                                                      u16* __restrict__ ssrc) {
  __shared__ u32 sc[256], cnt[256], cur[256];
  __shared__ u32 s_pb;
  int p = blockIdx.x, t = threadIdx.x;
  // pbase[p] via LDS scan of psize
  u32 v = (t < NPART) ? psize[t] : 0;
  sc[t] = v;
  __syncthreads();
#pragma unroll
  for (int d = 1; d < 256; d <<= 1) {
    u32 x = (t >= d) ? sc[t - d] : 0;
    __syncthreads();
    sc[t] += x;
    __syncthreads();
  }
  if (t == p) s_pb = sc[t] - v;
  cnt[t] = 0;
  __syncthreads();
  u32 pb = s_pb;
  int sz = (int)psize[p];
  for (int i = t; i < sz; i += 256)
    atomicAdd(&cnt[(part_buf[pb + i] >> 16) & 255u], 1);
  __syncthreads();
  u32 val = cnt[t];
  sc[t] = val;
  __syncthreads();
#pragma unroll
  for (int d = 1; d < 256; d <<= 1) {
    u32 x = (t >= d) ? sc[t - d] : 0;
    __syncthreads();
    sc[t] += x;
    __syncthreads();
  }
  u32 excl = sc[t] - val;
  int node = (p << 8) + t;
  if (node <= NN) offs[node] = (int)(pb + excl);
  cur[t] = excl;
  __syncthreads();
  for (int i = t; i < sz; i += 256) {
    u32 w = part_buf[pb + i];
    u32 slot = atomicAdd(&cur[(w >> 16) & 255u], 1);
    ssrc[pb + slot] = (u16)(w & 0xffffu);
  }
}

// ---------------- aggregation: full-row uint4 gather, wave per node ----------------
// Integer-grid accumulation: quantize to 2^-K grid, add integers in fp32 (all
// partials < 2^24 -> every add exact -> order-independent/deterministic).
#define ACC8Q(V, S) { acc[0] += rintf(bflo(V.x) * S); acc[1] += rintf(bfhi(V.x) * S); \
                      acc[2] += rintf(bflo(V.y) * S); acc[3] += rintf(bfhi(V.y) * S); \
                      acc[4] += rintf(bflo(V.z) * S); acc[5] += rintf(bfhi(V.z) * S); \
                      acc[6] += rintf(bflo(V.w) * S); acc[7] += rintf(bfhi(V.w) * S); }

// agg0: A0 [NN][LDA0], gather h0 (cols 128..255, 16 lanes x 16B, 4 edge-groups).
__global__ __launch_bounds__(256) void agg0_kernel(u16* __restrict__ A0,
                                                   const int* __restrict__ offs,
                                                   const u16* __restrict__ ssrc) {
  const float S = 8192.0f, INV = 1.0f / 8192.0f;   // 2^13
  int node = blockIdx.x * 4 + (threadIdx.x >> 6);
  int lane = threadIdx.x & 63;
  int l15 = lane & 15, eh = lane >> 4;    // eh in 0..3
  int s = offs[node], e = offs[node + 1];
  float acc[8] = {0.f, 0.f, 0.f, 0.f, 0.f, 0.f, 0.f, 0.f};
  int i = s;
  for (; i + 16 <= e; i += 16) {
    uint4 w0 = *(const uint4*)&A0[(int)ssrc[i + eh] * LDA0 + 128 + l15 * 8];
    uint4 w1 = *(const uint4*)&A0[(int)ssrc[i + 4 + eh] * LDA0 + 128 + l15 * 8];
    uint4 w2 = *(const uint4*)&A0[(int)ssrc[i + 8 + eh] * LDA0 + 128 + l15 * 8];
    uint4 w3 = *(const uint4*)&A0[(int)ssrc[i + 12 + eh] * LDA0 + 128 + l15 * 8];
    ACC8Q(w0, S); ACC8Q(w1, S); ACC8Q(w2, S); ACC8Q(w3, S);
  }
  for (; i + 4 <= e; i += 4) {
    uint4 w0 = *(const uint4*)&A0[(int)ssrc[i + eh] * LDA0 + 128 + l15 * 8];
    ACC8Q(w0, S);
  }
  if (i + eh < e) {
    uint4 w0 = *(const uint4*)&A0[(int)ssrc[i + eh] * LDA0 + 128 + l15 * 8];
    ACC8Q(w0, S);
  }
#pragma unroll
  for (int j = 0; j < 8; j++) {
    acc[j] += __shfl_xor(acc[j], 16);
    acc[j] += __shfl_xor(acc[j], 32);
  }
  if (lane < 16) {
    uint4 o;
    o.x = (u32)f2bf(acc[0] * INV) | ((u32)f2bf(acc[1] * INV) << 16);
    o.y = (u32)f2bf(acc[2] * INV) | ((u32)f2bf(acc[3] * INV) << 16);
    o.z = (u32)f2bf(acc[4] * INV) | ((u32)f2bf(acc[5] * INV) << 16);
    o.w = (u32)f2bf(acc[6] * INV) | ((u32)f2bf(acc[7] * INV) << 16);
    *(uint4*)&A0[node * LDA0 + l15 * 8] = o;
  }
}

// agg1: A1 [NN][512] (on d_out), gather h1 (cols 256..511, 32 lanes x 16B).
__global__ __launch_bounds__(256) void agg1_kernel(u16* __restrict__ A1,
                                                   const int* __restrict__ offs,
                                                   const u16* __restrict__ ssrc) {
  const float S = 256.0f, INV = 1.0f / 256.0f;     // 2^8
  int node = blockIdx.x * 4 + (threadIdx.x >> 6);
  int lane = threadIdx.x & 63;
  int l31 = lane & 31, eh = lane >> 5;    // eh in 0..1
  int s = offs[node], e = offs[node + 1];
  float acc[8] = {0.f, 0.f, 0.f, 0.f, 0.f, 0.f, 0.f, 0.f};
  int i = s;
  for (; i + 8 <= e; i += 8) {
    uint4 w0 = *(const uint4*)&A1[(int)ssrc[i + eh] * 512 + 256 + l31 * 8];
    uint4 w1 = *(const uint4*)&A1[(int)ssrc[i + 2 + eh] * 512 + 256 + l31 * 8];
    uint4 w2 = *(const uint4*)&A1[(int)ssrc[i + 4 + eh] * 512 + 256 + l31 * 8];
    uint4 w3 = *(const uint4*)&A1[(int)ssrc[i + 6 + eh] * 512 + 256 + l31 * 8];
    ACC8Q(w0, S); ACC8Q(w1, S); ACC8Q(w2, S); ACC8Q(w3, S);
  }
  for (; i + 2 <= e; i += 2) {
    uint4 w0 = *(const uint4*)&A1[(int)ssrc[i + eh] * 512 + 256 + l31 * 8];
    ACC8Q(w0, S);
  }
  if (i + eh < e) {
    uint4 w0 = *(const uint4*)&A1[(int)ssrc[i + eh] * 512 + 256 + l31 * 8];
    ACC8Q(w0, S);
  }
#pragma unroll
  for (int j = 0; j < 8; j++) acc[j] += __shfl_xor(acc[j], 32);
  if (eh == 0) {
    uint4 o;
    o.x = (u32)f2bf(acc[0] * INV) | ((u32)f2bf(acc[1] * INV) << 16);
    o.y = (u32)f2bf(acc[2] * INV) | ((u32)f2bf(acc[3] * INV) << 16);
    o.z = (u32)f2bf(acc[4] * INV) | ((u32)f2bf(acc[5] * INV) << 16);
    o.w = (u32)f2bf(acc[6] * INV) | ((u32)f2bf(acc[7] * INV) << 16);
    *(uint4*)&A1[node * 512 + l31 * 8] = o;
  }
}

// ---------------- GEMM: C[128 rows x 256 cols per block] = A @ Wt^T + b ----------------
// 512 threads, 8 waves; wave w: rows (w&3)*32..+32, cols (w>>2)*128..+128.
// acc[4] f32x16 = 64 VGPR -> no spill (BM=256/acc[8] spilled: VGPR=100 < 128 needed,
// WRITE_SIZE blew up to 286MB scratch traffic — round 19 post-mortem).
template <int K, int LDA, bool DROP>
__global__ __launch_bounds__(512) void gemm_kernel(const u16* __restrict__ A,
                                                   const u16* __restrict__ Wt,
                                                   const float* __restrict__ bias,
                                                   u16* __restrict__ outB,
                                                   float* __restrict__ outF,
                                                   u32 ka, u32 kb) {
  constexpr int BK = 64;
  constexpr int LDP = BK + 8;             // 72 u16 per LDS row
  __shared__ __align__(16) u16 Alds[128 * LDP];   // 18.4 KB
  __shared__ __align__(16) u16 Blds[256 * LDP];   // 36.9 KB
  const int tid = threadIdx.x;
  const int row0 = blockIdx.x * 128;
  const int lane = tid & 63;
  const int wid = tid >> 6;
  const int wr = wid & 3;                 // row quarter: 0..3
  const int wc = wid >> 2;                // col half: 0,1
  const int l31 = lane & 31;
  const int lkhi = (lane >> 5) * 8;

  f32x16 acc[4];
#pragma unroll
  for (int i = 0; i < 4; i++)
#pragma unroll
    for (int j = 0; j < 16; j++) acc[i][j] = 0.0f;

#pragma unroll
  for (int kc = 0; kc < K / BK; kc++) {
#pragma unroll
    for (int i = 0; i < 2; i++) {
      int id = tid + i * 512;
      int r = id >> 3, c = id & 7;
      int rg = row0 + r; if (rg > NN - 1) rg = NN - 1;
      *(uint4*)&Alds[r * LDP + c * 8] =
          *(const uint4*)&A[(size_t)rg * LDA + kc * BK + c * 8];
    }
#pragma unroll
    for (int i = 0; i < 4; i++) {
      int id = tid + i * 512;
      int r = id >> 3, c = id & 7;
      *(uint4*)&Blds[r * LDP + c * 8] =
          *(const uint4*)&Wt[(size_t)r * K + kc * BK + c * 8];
    }
    __syncthreads();
#pragma unroll
    for (int ks = 0; ks < BK / 16; ks++) {
      bf16x8 a = *(const bf16x8*)&Alds[(wr * 32 + l31) * LDP + ks * 16 + lkhi];
#pragma unroll
      for (int ct = 0; ct < 4; ct++) {
        bf16x8 b = *(const bf16x8*)&Blds[(wc * 128 + ct * 32 + l31) * LDP + ks * 16 + lkhi];
        acc[ct] = __builtin_amdgcn_mfma_f32_32x32x16_bf16(a, b, acc[ct], 0, 0, 0);
      }
    }
    __syncthreads();
  }

  // epilogue: C/D layout (m74/m101): col = lane&31, row = (r&3)+8*(r>>2)+4*(lane>>5)
#pragma unroll
  for (int ct = 0; ct < 4; ct++) {
    int col = wc * 128 + ct * 32 + l31;
    float bv = bias[col];
#pragma unroll
    for (int r = 0; r < 16; r++) {
      int row = row0 + wr * 32 + (r & 3) + 8 * (r >> 2) + 4 * (lane >> 5);
      if (row < NN) {
        float v = acc[ct][r] + bv;
        v = fmaxf(v, 0.0f);
        if constexpr (DROP) {
          u32 j = (u32)row * 256u + (u32)col;
          v = (u01(tfbits(ka, kb, j)) < 0.4f) ? v * 2.5f : 0.0f;
          outB[(size_t)row * 512 + 256 + col] = f2bf(v);
        } else {
          outF[(size_t)row * 256 + col] = v;
        }
      }
    }
  }
}

// ---------------- host launch ----------------
extern "C" void kernel_launch(void* const* d_in, const int* in_sizes, int n_in,
                              void* d_out, int out_size, void* d_ws, size_t ws_size,
                              hipStream_t stream) {
  (void)in_sizes; (void)n_in; (void)out_size; (void)ws_size;
  const float* x       = (const float*)d_in[0];
  const int*   ei      = (const int*)d_in[1];
  const float* w_rel0  = (const float*)d_in[2];
  const float* b_rel0  = (const float*)d_in[3];
  const float* w_root0 = (const float*)d_in[4];
  const float* w_rel1  = (const float*)d_in[5];
  const float* b_rel1  = (const float*)d_in[6];
  const float* w_root1 = (const float*)d_in[7];
  float* out = (float*)d_out;

  u32 k0a, k0b, k1a, k1b;
  tf2x32(0u, 42u, 0u, 0u, k0a, k0b);
  tf2x32(0u, 42u, 0u, 1u, k1a, k1b);

  uint8_t* p = (uint8_t*)d_ws;
  auto alloc = [&](size_t bytes) {
    uint8_t* r = p;
    p += (bytes + 255) & ~(size_t)255;
    return r;
  };
  u16* A0       = (u16*)alloc((size_t)NN * LDA0 * 2);  // 28.8 MB
  u16* Wt0      = (u16*)alloc(256 * 256 * 2);
  u16* Wt1      = (u16*)alloc(256 * 512 * 2);
  int* offs     = (int*)alloc((size_t)(NN + 1) * 4);
  u16* ssrc     = (u16*)alloc((size_t)NE * 2);
  u32* epack    = (u32*)alloc((size_t)NE * 4);
  u32* pcnt     = (u32*)alloc((size_t)NB1 * NPART * 4);
  u32* pofs     = (u32*)alloc((size_t)NPART * NB1 * 4);
  u32* psize    = (u32*)alloc((size_t)NPART * 4);
  u32* part_buf = (u32*)alloc((size_t)NE * 4);

  u16* A1 = (u16*)d_out;   // A1 [50000][512] bf16 aliases d_out

  const int GEMM_NB = (NN + 127) / 128;   // 391

  prologue_kernel<<<PRO_TOT, 256, 0, stream>>>(x, ei, w_rel0, w_root0, w_rel1,
                                               w_root1, A0, epack, Wt0, Wt1,
                                               k0a, k0b);
  p1_count_kernel<<<NB1, 256, 0, stream>>>(epack, pcnt);
  p1b_scan_kernel<<<NPART, 256, 0, stream>>>(pcnt, pofs, psize);
  p1d_pscatter_kernel<<<NB1, 256, 0, stream>>>(epack, pofs, psize, part_buf);
  p2_sort_kernel<<<NPART, 256, 0, stream>>>(part_buf, psize, offs, ssrc);
  agg0_kernel<<<12500, 256, 0, stream>>>(A0, offs, ssrc);
  gemm_kernel<256, LDA0, true><<<GEMM_NB, 512, 0, stream>>>(A0, Wt0, b_rel0, A1, nullptr, k1a, k1b);
  agg1_kernel<<<12500, 256, 0, stream>>>(A1, offs, ssrc);
  gemm_kernel<512, 512, false><<<GEMM_NB, 512, 0, stream>>>(A1, Wt1, b_rel1, nullptr, out, 0u, 0u);
}